// Round 6
// baseline (619.168 us; speedup 1.0000x reference)
//
#include <hip/hip_runtime.h>

#define B_ 8
#define S_ 1024
#define D_ 512
#define H_ 8
#define HD_ 64
#define F_ 2048

typedef unsigned short u16;  // bf16 bit pattern
typedef unsigned int u32;
typedef __attribute__((ext_vector_type(8))) short bf16x8;
typedef __attribute__((ext_vector_type(4))) float f32x4;

__device__ __forceinline__ float bf2f(u16 u) {
  union { unsigned int i; float f; } v; v.i = ((unsigned int)u) << 16; return v.f;
}
__device__ __forceinline__ u16 f2bf(float f) {
  union { float f; unsigned int i; } v; v.f = f;
  unsigned int r = v.i + 0x7fffu + ((v.i >> 16) & 1u);  // round-nearest-even
  return (u16)(r >> 16);
}

__device__ __forceinline__ void gl2lds16(const u16* g, u16* lds) {
  __builtin_amdgcn_global_load_lds(
      (const __attribute__((address_space(1))) unsigned int*)g,
      (__attribute__((address_space(3))) unsigned int*)lds, 16, 0, 0);
}

// ---------------- weight fp32 -> bf16 conversion ----------------
__global__ __launch_bounds__(256) void cvt_w_k(const float* __restrict__ wq, const float* __restrict__ wk,
                                               const float* __restrict__ wv, const float* __restrict__ wo,
                                               const float* __restrict__ wf1, const float* __restrict__ wf2,
                                               u16* __restrict__ dst) {
  size_t gid = (size_t)blockIdx.x * 256 + threadIdx.x;
  size_t e0 = gid * 4;
  const float* src; size_t loc;
  if      (e0 <  262144) { src = wq;  loc = e0; }
  else if (e0 <  524288) { src = wk;  loc = e0 -  262144; }
  else if (e0 <  786432) { src = wv;  loc = e0 -  524288; }
  else if (e0 < 1048576) { src = wo;  loc = e0 -  786432; }
  else if (e0 < 2097152) { src = wf1; loc = e0 - 1048576; }
  else                   { src = wf2; loc = e0 - 2097152; }
  float4 v = *(const float4*)(src + loc);
  ushort4 o; o.x = f2bf(v.x); o.y = f2bf(v.y); o.z = f2bf(v.z); o.w = f2bf(v.w);
  *(ushort4*)(dst + e0) = o;
}

// ---------------- RMSNorm: one block per row of 512, vectorized ----------------
template <int IN_BF16>
__global__ __launch_bounds__(256) void rmsnorm_k(const void* __restrict__ xv,
                                                 const float* __restrict__ w,
                                                 u16* __restrict__ out) {
  int row = blockIdx.x;
  int tid = threadIdx.x;
  float x0, x1;
  if (IN_BF16) {
    u32 v = ((const u32*)((const u16*)xv + (size_t)row * D_))[tid];
    x0 = bf2f((u16)(v & 0xffffu)); x1 = bf2f((u16)(v >> 16));
  } else {
    float2 v = ((const float2*)((const float*)xv + (size_t)row * D_))[tid];
    x0 = v.x; x1 = v.y;
  }
  float s = x0 * x0 + x1 * x1;
#pragma unroll
  for (int off = 32; off >= 1; off >>= 1) s += __shfl_xor(s, off, 64);
  __shared__ float red[4];
  int lane = tid & 63, wid = tid >> 6;
  if (lane == 0) red[wid] = s;
  __syncthreads();
  float tot = red[0] + red[1] + red[2] + red[3];
  float inv = rsqrtf(tot * (1.0f / D_) + 1e-6f);
  float2 wv = ((const float2*)w)[tid];
  u32 o = (u32)f2bf(x0 * inv * wv.x) | ((u32)f2bf(x1 * inv * wv.y) << 16);
  ((u32*)(out + (size_t)row * D_))[tid] = o;
}

// ------------- MFMA GEMM (m97 structure), B-transposed form -------------
template <int RELU, int RMODE, int OF32, int BM>
__global__ __launch_bounds__(256) void gemm_mfma_k(const u16* __restrict__ A,
                                                   const u16* __restrict__ W,
                                                   const void* __restrict__ Rv,
                                                   void* __restrict__ Cv,
                                                   int M, int N, int K) {
  constexpr int MI  = BM / 32;       // acc fragments in M per wave
  constexpr int ACH = BM / 16;       // A chunks (16 rows each)
  __shared__ __align__(16) u16 As[BM * 32];
  __shared__ __align__(16) u16 Bs[128 * 32];
  int tid = threadIdx.x;
  int w = tid >> 6, l = tid & 63;
  int quad = l >> 4, l16 = l & 15;
  int m0 = blockIdx.y * BM, n0 = blockIdx.x * 128;
  int wr = (w >> 1) * (BM / 2), wc = (w & 1) * 64;

  int c_sw = (l & 3) ^ ((l >> 2) & 3);
  int r_in = l >> 2;
  int swz = quad ^ (l16 & 3);

  f32x4 acc[MI][4];
#pragma unroll
  for (int i = 0; i < MI; i++)
#pragma unroll
    for (int j = 0; j < 4; j++) acc[i][j] = (f32x4)(0.0f);

  for (int k0 = 0; k0 < K; k0 += 32) {
    __syncthreads();
#pragma unroll
    for (int t = 0; t < (ACH + 8) / 4; t++) {
      int ch = w * ((ACH + 8) / 4) + t;
      const u16* src; u16* dst;
      if (ch < ACH) { src = A + (size_t)(m0 + ch * 16 + r_in) * K;         dst = As + ch * 512; }
      else          { src = W + (size_t)(n0 + (ch - ACH) * 16 + r_in) * K; dst = Bs + (ch - ACH) * 512; }
      gl2lds16(src + k0 + c_sw * 8, dst);
    }
    __syncthreads();
    bf16x8 af[MI], bf[4];
#pragma unroll
    for (int i = 0; i < MI; i++)
      af[i] = *(const bf16x8*)(As + (wr + i * 16 + l16) * 32 + swz * 8);
#pragma unroll
    for (int j = 0; j < 4; j++)
      bf[j] = *(const bf16x8*)(Bs + (wc + j * 16 + l16) * 32 + swz * 8);
#pragma unroll
    for (int i = 0; i < MI; i++)
#pragma unroll
      for (int j = 0; j < 4; j++)
        acc[i][j] = __builtin_amdgcn_mfma_f32_16x16x32_bf16(af[i], bf[j], acc[i][j], 0, 0, 0);
  }

#pragma unroll
  for (int i = 0; i < MI; i++)
#pragma unroll
    for (int r = 0; r < 4; r++) {
      int mrow = m0 + wr + i * 16 + quad * 4 + r;
      size_t base = (size_t)mrow * N + n0 + wc + l16;
#pragma unroll
      for (int j = 0; j < 4; j++) {
        float v = acc[i][j][r];
        if (RELU) v = fmaxf(v, 0.0f);
        if (RMODE == 1) v += ((const float*)Rv)[base + j * 16];
        if (RMODE == 2) v += bf2f(((const u16*)Rv)[base + j * 16]);
        if (OF32) ((float*)Cv)[base + j * 16] = v;
        else      ((u16*)Cv)[base + j * 16]   = f2bf(v);
      }
    }
}

// ------------- V transpose: qkv v-cols -> Vt[b][h][d][s] -------------
__global__ __launch_bounds__(256) void transpose_v_k(const u16* __restrict__ qkv,
                                                     u16* __restrict__ vt) {
  __shared__ u16 T[64][72];  // [dim][key]
  int t = threadIdx.x;
  int s0 = blockIdx.x * 64, h = blockIdx.y, b = blockIdx.z;
  int skey = t >> 3, dch = (t & 7) * 8;
  int rot = dch >> 3;  // rotate write order so dch groups hit different banks
#pragma unroll
  for (int rnd = 0; rnd < 2; rnd++) {
    int s = s0 + skey + rnd * 32;
    bf16x8 vv = *(const bf16x8*)(qkv + ((size_t)(b * S_) + s) * 1536 + 1024 + h * HD_ + dch);
#pragma unroll
    for (int i = 0; i < 8; i++) {
      int ii = (i + rot) & 7;
      T[dch + ii][skey + rnd * 32] = (u16)((short*)&vv)[ii];
    }
  }
  __syncthreads();
  int d = t >> 2, kc = (t & 3) * 16;
  bf16x8 a0 = *(const bf16x8*)(&T[d][kc]);
  bf16x8 a1 = *(const bf16x8*)(&T[d][kc + 8]);
  u16* dst = vt + ((size_t)(b * H_ + h) * HD_ + d) * S_ + s0 + kc;
  *(bf16x8*)dst       = a0;
  *(bf16x8*)(dst + 8) = a1;
}

// ------------- attention v8: barrier-free register-pipelined -------------
// No block-wide phases at all: K-frags + bias double-buffered in registers
// (parity-unrolled), V-frags issued at tile start and consumed one compute
// phase later (T14). K/V/bias are all per-lane-contiguous 16B loads (swapped
// QK^T layout + pre-transposed V), so staging-via-LDS bought nothing but the
// barrier. Each wave is an independent flash-attn pipeline; waves on a SIMD
// stagger naturally -> MFMA and VALU pipes interleave instead of phase-lock.
// ~190 VGPR -> 2 waves/SIMD, but ~20 outstanding 1KB loads/wave keeps
// in-flight bytes/CU above the 6.3TB/s requirement.
#define FIXED_M 20.0f

__global__ __launch_bounds__(256, 2) void attn_v8_k(const u16* __restrict__ qkv,
                                                    const u16* __restrict__ vt,
                                                    const float* __restrict__ bias,
                                                    u16* __restrict__ ctx) {
  int tid = threadIdx.x;
  int w = tid >> 6, lane = tid & 63;
  int quad = lane >> 4, l16 = lane & 15;
  int h = blockIdx.y, b = blockIdx.z;
  int q0 = blockIdx.x * 64;   // 4 waves x 16 q-rows

  __shared__ __align__(16) u16 Pl[4][16 * 72];  // per-wave P [q][key], pad 64->72

  const u16* qrow = qkv + ((size_t)(b * S_) + q0 + w * 16 + l16) * 1536 + h * HD_;
  bf16x8 qf0 = *(const bf16x8*)(qrow + quad * 8);
  bf16x8 qf1 = *(const bf16x8*)(qrow + 32 + quad * 8);

  float lr = 0.0f;          // per-lane partial row-sum for q-row l16
  f32x4 Oacc[4];
#pragma unroll
  for (int nt = 0; nt < 4; nt++) Oacc[nt] = (f32x4)(0.0f);

  // swapped layout: lane l16 owns q-row l16; keys quad*4+r per 16-key group
  const float* bln = bias + ((size_t)((b * H_ + h) * S_) + q0 + w * 16 + l16) * S_ + quad * 4;
  const u16* kbase = qkv + (size_t)(b * S_) * 1536 + 512 + h * HD_ + quad * 8;
  const u16* vbase = vt + (size_t)((b * H_ + h) * HD_) * S_ + quad * 8;

  bf16x8 kA[8], kB[8];      // K-frag double buffer (parity-static, rule #20)
  float4 bA[4], bB[4];      // bias double buffer

  // prologue: tile 0's K + bias
#pragma unroll
  for (int g = 0; g < 4; g++) {
    const u16* kp = kbase + (size_t)(g * 16 + l16) * 1536;
    kA[g * 2]     = *(const bf16x8*)kp;
    kA[g * 2 + 1] = *(const bf16x8*)(kp + 32);
    bA[g] = *(const float4*)(bln + g * 16);
  }

  auto body = [&](int t, bf16x8 (&kc)[8], bf16x8 (&kn)[8],
                  float4 (&bc)[4], float4 (&bn)[4]) {
    int kt = t * 64;
    // 1. issue V(t): consumed after QK+softmax (~400cy of flight time)
    bf16x8 vf[8];
#pragma unroll
    for (int nt = 0; nt < 4; nt++) {
      const u16* vp = vbase + (size_t)(nt * 16 + l16) * S_ + kt;
      vf[nt * 2]     = *(const bf16x8*)vp;
      vf[nt * 2 + 1] = *(const bf16x8*)(vp + 32);
    }
    // 2. issue K(t+1) + bias(t+1): a full tile of flight time
    if (t < 15) {
#pragma unroll
      for (int g = 0; g < 4; g++) {
        const u16* kp = kbase + (size_t)(kt + 64 + g * 16 + l16) * 1536;
        kn[g * 2]     = *(const bf16x8*)kp;
        kn[g * 2 + 1] = *(const bf16x8*)(kp + 32);
        bn[g] = *(const float4*)(bln + kt + 64 + g * 16);
      }
    }
    // 3. S^T = K Q^T from registers (loaded last tile)
    f32x4 sg[4];
    __builtin_amdgcn_s_setprio(1);
#pragma unroll
    for (int g = 0; g < 4; g++) {
      f32x4 a = (f32x4)(0.0f);
      a = __builtin_amdgcn_mfma_f32_16x16x32_bf16(kc[g * 2], qf0, a, 0, 0, 0);
      a = __builtin_amdgcn_mfma_f32_16x16x32_bf16(kc[g * 2 + 1], qf1, a, 0, 0, 0);
      sg[g] = a;
    }
    __builtin_amdgcn_s_setprio(0);
    // 4. bias add + fixed-ref exp; lane owns q-row l16, keys g*16+quad*4+r
#pragma unroll
    for (int g = 0; g < 4; g++) {
      float4 bf4 = bc[g];
      float p0 = __expf(sg[g][0] + bf4.x - FIXED_M);
      float p1 = __expf(sg[g][1] + bf4.y - FIXED_M);
      float p2 = __expf(sg[g][2] + bf4.z - FIXED_M);
      float p3 = __expf(sg[g][3] + bf4.w - FIXED_M);
      lr += (p0 + p1) + (p2 + p3);
      ushort4 pw;
      pw.x = f2bf(p0); pw.y = f2bf(p1); pw.z = f2bf(p2); pw.w = f2bf(p3);
      *(ushort4*)(&Pl[w][l16 * 72 + g * 16 + quad * 4]) = pw;
    }
    // 5. P relayout: wave-local LDS round trip (no barrier)
    bf16x8 pf0 = *(const bf16x8*)(&Pl[w][l16 * 72 + quad * 8]);
    bf16x8 pf1 = *(const bf16x8*)(&Pl[w][l16 * 72 + 32 + quad * 8]);
    // 6. O += P V from registers (V issued at step 1)
    __builtin_amdgcn_s_setprio(1);
#pragma unroll
    for (int nt = 0; nt < 4; nt++) {
      Oacc[nt] = __builtin_amdgcn_mfma_f32_16x16x32_bf16(pf0, vf[nt * 2], Oacc[nt], 0, 0, 0);
      Oacc[nt] = __builtin_amdgcn_mfma_f32_16x16x32_bf16(pf1, vf[nt * 2 + 1], Oacc[nt], 0, 0, 0);
    }
    __builtin_amdgcn_s_setprio(0);
  };

#pragma unroll 1
  for (int tt = 0; tt < 16; tt += 2) {
    body(tt,     kA, kB, bA, bB);
    body(tt + 1, kB, kA, bB, bA);
  }

  // row-sum: lane partials -> full sum over the 4 quads (keys partition)
  float s = lr;
  s += __shfl_xor(s, 16, 64);
  s += __shfl_xor(s, 32, 64);
  size_t obase = ((size_t)(b * S_) + q0 + w * 16) * D_ + h * HD_;
#pragma unroll
  for (int r = 0; r < 4; r++) {
    float inv = 1.0f / __shfl(s, quad * 4 + r, 64);
    int qr = quad * 4 + r;
#pragma unroll
    for (int nt = 0; nt < 4; nt++) {
      ctx[obase + (size_t)qr * D_ + nt * 16 + l16] = f2bf(Oacc[nt][r] * inv);
    }
  }
}

extern "C" void kernel_launch(void* const* d_in, const int* in_sizes, int n_in,
                              void* d_out, int out_size, void* d_ws, size_t ws_size,
                              hipStream_t stream) {
  const float* Wk   = (const float*)d_in[0];  // primals_1 [D,D] -> K proj
  const float* Wo   = (const float*)d_in[1];  // primals_2 [D,D] -> out proj
  const float* Wq   = (const float*)d_in[2];  // primals_3 [D,D] -> Q proj
  const float* Wv   = (const float*)d_in[3];  // primals_4 [D,D] -> V proj
  const float* g1   = (const float*)d_in[4];  // primals_5 [D]
  const float* Wf1  = (const float*)d_in[5];  // primals_6 [F,D]
  const float* Wf2  = (const float*)d_in[6];  // primals_7 [D,F]
  const float* g2   = (const float*)d_in[7];  // primals_8 [D]
  const float* X    = (const float*)d_in[8];  // primals_9 [B,S,D] fp32
  const float* bias = (const float*)d_in[9];  // primals_10 [B,H,S,S] fp32
  float* out = (float*)d_out;

  const size_t MD = (size_t)B_ * S_ * D_;       // 4,194,304
  u16* wbf   = (u16*)d_ws;
  u16* Wqkvb = wbf;               // [1536,512] = Wq|Wk|Wv
  u16* Wob   = wbf +  786432;
  u16* Wf1b  = wbf + 1048576;
  u16* Wf2b  = wbf + 2097152;
  u16* h     = wbf + 3145728;     // h, later h2
  u16* qkv   = h + MD;            // [8192][1536]; later x1
  u16* vtb   = qkv + 3 * MD;      // [B,H,64,S]
  u16* ctx   = vtb + MD;
  u16* ff    = ctx + MD;          // [8192][2048]
  u16* x1    = qkv;
  u16* h2    = h;

  dim3 blk(256);
  const int M = B_ * S_;

  // 0. weights -> bf16
  cvt_w_k<<<3072, blk, 0, stream>>>(Wq, Wk, Wv, Wo, Wf1, Wf2, wbf);

  // 1. h = rmsnorm(x, g1)
  rmsnorm_k<0><<<M, blk, 0, stream>>>(X, g1, h);

  // 2. qkv = h @ Wqkv^T  (M=8192, N=1536, K=512)
  dim3 gqkv(1536 / 128, M / 128);   // (12, 64) = 768 blocks, 3/CU
  gemm_mfma_k<0, 0, 0, 128><<<gqkv, blk, 0, stream>>>(h, Wqkvb, nullptr, qkv, M, 1536, D_);

  // 3. Vt = transpose(v)
  dim3 gt(S_ / 64, H_, B_);
  transpose_v_k<<<gt, blk, 0, stream>>>(qkv, vtb);

  // 4. ctx = softmax(q k^T + bias) v  (barrier-free register pipeline)
  dim3 ga(S_ / 64, H_, B_);           // (16,8,8) = 1024 blocks
  attn_v8_k<<<ga, blk, 0, stream>>>(qkv, vtb, bias, ctx);

  // 5. x1 = x + ctx @ Wo^T (fp32 residual, bf16 out)
  dim3 g512(D_ / 128, M / 128);
  gemm_mfma_k<0, 1, 0, 128><<<g512, blk, 0, stream>>>(ctx, Wob, X, x1, M, D_, D_);

  // 6. h2 = rmsnorm(x1, g2)
  rmsnorm_k<1><<<M, blk, 0, stream>>>(x1, g2, h2);

  // 7. ff = relu(h2 @ Wf1^T)
  dim3 gff1(F_ / 128, M / 128);     // (16, 64)
  gemm_mfma_k<1, 0, 0, 128><<<gff1, blk, 0, stream>>>(h2, Wf1b, nullptr, ff, M, F_, D_);

  // 8. out = x1 + ff @ Wf2^T (bf16 residual, fp32 out)
  gemm_mfma_k<0, 2, 1, 128><<<g512, blk, 0, stream>>>(ff, Wf2b, x1, out, M, D_, F_);
}

// Round 7
// 567.908 us; speedup vs baseline: 1.0903x; 1.0903x over previous
//
#include <hip/hip_runtime.h>

#define B_ 8
#define S_ 1024
#define D_ 512
#define H_ 8
#define HD_ 64
#define F_ 2048

typedef unsigned short u16;  // bf16 bit pattern
typedef unsigned int u32;
typedef __attribute__((ext_vector_type(8))) short bf16x8;
typedef __attribute__((ext_vector_type(4))) float f32x4;

__device__ __forceinline__ float bf2f(u16 u) {
  union { unsigned int i; float f; } v; v.i = ((unsigned int)u) << 16; return v.f;
}
__device__ __forceinline__ u16 f2bf(float f) {
  union { float f; unsigned int i; } v; v.f = f;
  unsigned int r = v.i + 0x7fffu + ((v.i >> 16) & 1u);  // round-nearest-even
  return (u16)(r >> 16);
}

__device__ __forceinline__ void gl2lds16(const u16* g, u16* lds) {
  __builtin_amdgcn_global_load_lds(
      (const __attribute__((address_space(1))) unsigned int*)g,
      (__attribute__((address_space(3))) unsigned int*)lds, 16, 0, 0);
}

// ---------------- weight fp32 -> bf16 conversion ----------------
__global__ __launch_bounds__(256) void cvt_w_k(const float* __restrict__ wq, const float* __restrict__ wk,
                                               const float* __restrict__ wv, const float* __restrict__ wo,
                                               const float* __restrict__ wf1, const float* __restrict__ wf2,
                                               u16* __restrict__ dst) {
  size_t gid = (size_t)blockIdx.x * 256 + threadIdx.x;
  size_t e0 = gid * 4;
  const float* src; size_t loc;
  if      (e0 <  262144) { src = wq;  loc = e0; }
  else if (e0 <  524288) { src = wk;  loc = e0 -  262144; }
  else if (e0 <  786432) { src = wv;  loc = e0 -  524288; }
  else if (e0 < 1048576) { src = wo;  loc = e0 -  786432; }
  else if (e0 < 2097152) { src = wf1; loc = e0 - 1048576; }
  else                   { src = wf2; loc = e0 - 2097152; }
  float4 v = *(const float4*)(src + loc);
  ushort4 o; o.x = f2bf(v.x); o.y = f2bf(v.y); o.z = f2bf(v.z); o.w = f2bf(v.w);
  *(ushort4*)(dst + e0) = o;
}

// ---------------- RMSNorm: one block per row of 512, vectorized ----------------
template <int IN_BF16>
__global__ __launch_bounds__(256) void rmsnorm_k(const void* __restrict__ xv,
                                                 const float* __restrict__ w,
                                                 u16* __restrict__ out) {
  int row = blockIdx.x;
  int tid = threadIdx.x;
  float x0, x1;
  if (IN_BF16) {
    u32 v = ((const u32*)((const u16*)xv + (size_t)row * D_))[tid];
    x0 = bf2f((u16)(v & 0xffffu)); x1 = bf2f((u16)(v >> 16));
  } else {
    float2 v = ((const float2*)((const float*)xv + (size_t)row * D_))[tid];
    x0 = v.x; x1 = v.y;
  }
  float s = x0 * x0 + x1 * x1;
#pragma unroll
  for (int off = 32; off >= 1; off >>= 1) s += __shfl_xor(s, off, 64);
  __shared__ float red[4];
  int lane = tid & 63, wid = tid >> 6;
  if (lane == 0) red[wid] = s;
  __syncthreads();
  float tot = red[0] + red[1] + red[2] + red[3];
  float inv = rsqrtf(tot * (1.0f / D_) + 1e-6f);
  float2 wv = ((const float2*)w)[tid];
  u32 o = (u32)f2bf(x0 * inv * wv.x) | ((u32)f2bf(x1 * inv * wv.y) << 16);
  ((u32*)(out + (size_t)row * D_))[tid] = o;
}

// ------------- MFMA GEMM (m97 structure), B-transposed form -------------
template <int RELU, int RMODE, int OF32, int BM>
__global__ __launch_bounds__(256) void gemm_mfma_k(const u16* __restrict__ A,
                                                   const u16* __restrict__ W,
                                                   const void* __restrict__ Rv,
                                                   void* __restrict__ Cv,
                                                   int M, int N, int K) {
  constexpr int MI  = BM / 32;       // acc fragments in M per wave
  constexpr int ACH = BM / 16;       // A chunks (16 rows each)
  __shared__ __align__(16) u16 As[BM * 32];
  __shared__ __align__(16) u16 Bs[128 * 32];
  int tid = threadIdx.x;
  int w = tid >> 6, l = tid & 63;
  int quad = l >> 4, l16 = l & 15;
  int m0 = blockIdx.y * BM, n0 = blockIdx.x * 128;
  int wr = (w >> 1) * (BM / 2), wc = (w & 1) * 64;

  int c_sw = (l & 3) ^ ((l >> 2) & 3);
  int r_in = l >> 2;
  int swz = quad ^ (l16 & 3);

  f32x4 acc[MI][4];
#pragma unroll
  for (int i = 0; i < MI; i++)
#pragma unroll
    for (int j = 0; j < 4; j++) acc[i][j] = (f32x4)(0.0f);

  for (int k0 = 0; k0 < K; k0 += 32) {
    __syncthreads();
#pragma unroll
    for (int t = 0; t < (ACH + 8) / 4; t++) {
      int ch = w * ((ACH + 8) / 4) + t;
      const u16* src; u16* dst;
      if (ch < ACH) { src = A + (size_t)(m0 + ch * 16 + r_in) * K;         dst = As + ch * 512; }
      else          { src = W + (size_t)(n0 + (ch - ACH) * 16 + r_in) * K; dst = Bs + (ch - ACH) * 512; }
      gl2lds16(src + k0 + c_sw * 8, dst);
    }
    __syncthreads();
    bf16x8 af[MI], bf[4];
#pragma unroll
    for (int i = 0; i < MI; i++)
      af[i] = *(const bf16x8*)(As + (wr + i * 16 + l16) * 32 + swz * 8);
#pragma unroll
    for (int j = 0; j < 4; j++)
      bf[j] = *(const bf16x8*)(Bs + (wc + j * 16 + l16) * 32 + swz * 8);
#pragma unroll
    for (int i = 0; i < MI; i++)
#pragma unroll
      for (int j = 0; j < 4; j++)
        acc[i][j] = __builtin_amdgcn_mfma_f32_16x16x32_bf16(af[i], bf[j], acc[i][j], 0, 0, 0);
  }

#pragma unroll
  for (int i = 0; i < MI; i++)
#pragma unroll
    for (int r = 0; r < 4; r++) {
      int mrow = m0 + wr + i * 16 + quad * 4 + r;
      size_t base = (size_t)mrow * N + n0 + wc + l16;
#pragma unroll
      for (int j = 0; j < 4; j++) {
        float v = acc[i][j][r];
        if (RELU) v = fmaxf(v, 0.0f);
        if (RMODE == 1) v += ((const float*)Rv)[base + j * 16];
        if (RMODE == 2) v += bf2f(((const u16*)Rv)[base + j * 16]);
        if (OF32) ((float*)Cv)[base + j * 16] = v;
        else      ((u16*)Cv)[base + j * 16]   = f2bf(v);
      }
    }
}

// ------------- V transpose: qkv v-cols -> Vt[b][h][d][s] -------------
__global__ __launch_bounds__(256) void transpose_v_k(const u16* __restrict__ qkv,
                                                     u16* __restrict__ vt) {
  __shared__ u16 T[64][72];  // [dim][key]
  int t = threadIdx.x;
  int s0 = blockIdx.x * 64, h = blockIdx.y, b = blockIdx.z;
  int skey = t >> 3, dch = (t & 7) * 8;
  int rot = dch >> 3;  // rotate write order so dch groups hit different banks
#pragma unroll
  for (int rnd = 0; rnd < 2; rnd++) {
    int s = s0 + skey + rnd * 32;
    bf16x8 vv = *(const bf16x8*)(qkv + ((size_t)(b * S_) + s) * 1536 + 1024 + h * HD_ + dch);
#pragma unroll
    for (int i = 0; i < 8; i++) {
      int ii = (i + rot) & 7;
      T[dch + ii][skey + rnd * 32] = (u16)((short*)&vv)[ii];
    }
  }
  __syncthreads();
  int d = t >> 2, kc = (t & 3) * 16;
  bf16x8 a0 = *(const bf16x8*)(&T[d][kc]);
  bf16x8 a1 = *(const bf16x8*)(&T[d][kc + 8]);
  u16* dst = vt + ((size_t)(b * H_ + h) * HD_ + d) * S_ + s0 + kc;
  *(bf16x8*)dst       = a0;
  *(bf16x8*)(dst + 8) = a1;
}

// ------------- attention v9: bias through global_load_lds DMA -------------
// Diagnosis (R6): bias (268 MB, 85% of attn traffic) was always on plain
// register loads, which the compiler sinks to the use point -> ~2 KB/CU in
// flight (Little's law needs ~9 KB for 6.3 TB/s) -> attn stuck at 1.5 TB/s.
// Fix: bias staged via global_load_lds (unsinkable, issues where written),
// double-buffered, full-tile flight. Per-wave [16 rows][16 x 16B chunks],
// chunk-XOR c^(row&7): inverse-swizzled global src + linear DMA dest +
// swizzled ds_read_b128 (G21 both-sides discipline) -> conflict-free float4
// bias reads in the swapped-QK layout. 4-wave blocks (64 q-rows), LDS 73 KB,
// 2 blocks/CU; in-flight ~64 KB/CU >> 9 KB requirement.
#define FIXED_M 20.0f

__global__ __launch_bounds__(256, 2) void attn_v9_k(const u16* __restrict__ qkv,
                                                    const u16* __restrict__ vt,
                                                    const float* __restrict__ bias,
                                                    u16* __restrict__ ctx) {
  int tid = threadIdx.x;
  int w = tid >> 6, lane = tid & 63;
  int quad = lane >> 4, l16 = lane & 15;
  int h = blockIdx.y, b = blockIdx.z;
  int q0 = blockIdx.x * 64;   // 4 waves x 16 q-rows

  __shared__ __align__(16) u16 KV[2][4 * 2048];    // [dbuf][KsA|KsB|VsA|VsB]
  __shared__ __align__(16) u16 BiasL[2][4][2048];  // [dbuf][wave][16q x 64k fp32]
  __shared__ __align__(16) u16 Pl[4][16 * 72];     // per-wave P [q][key], pad 64->72

  // Q frags (swapped layout: Q is the MFMA B operand)
  const u16* qrow = qkv + ((size_t)(b * S_) + q0 + w * 16 + l16) * 1536 + h * HD_;
  bf16x8 qf0 = *(const bf16x8*)(qrow + quad * 8);
  bf16x8 qf1 = *(const bf16x8*)(qrow + 32 + quad * 8);

  float lr = 0.0f;          // per-lane partial row-sum for q-row l16
  f32x4 Oacc[4];
#pragma unroll
  for (int nt = 0; nt < 4; nt++) Oacc[nt] = (f32x4)(0.0f);

  const float* brow0 = bias + ((size_t)((b * H_ + h) * S_) + q0 + w * 16) * S_;

  // ---- staging: wave w owns one KV buffer (0:KsA 1:KsB 2:VsA 3:VsB) ----
  int kv_srow_base = lane >> 2;            // + i*16
  int kv_sc = lane & 3;
  // bias staging lane map: iteration i covers rows i*4 + (lane>>4)
  int b_rl_base = lane >> 4;               // + i*4
  int b_p = lane & 15;                     // physical 16B chunk

  auto stage = [&](u16* kvbuf, u16* bbuf, int kt) {
#pragma unroll
    for (int i = 0; i < 4; i++) {
      int srow = i * 16 + kv_srow_base;
      int slc = kv_sc ^ (srow & 3);        // m97 chunk swizzle (global side)
      const u16* src;
      if (w == 0)      src = qkv + ((size_t)(b * S_) + kt + srow) * 1536 + 512 + h * HD_ + slc * 8;
      else if (w == 1) src = qkv + ((size_t)(b * S_) + kt + srow) * 1536 + 544 + h * HD_ + slc * 8;
      else if (w == 2) src = vt + ((size_t)((b * H_ + h) * HD_) + srow) * S_ + kt + slc * 8;
      else             src = vt + ((size_t)((b * H_ + h) * HD_) + srow) * S_ + kt + 32 + slc * 8;
      gl2lds16(src, kvbuf + w * 2048 + i * 512);
    }
    // bias: per-wave 4 KB; logical chunk c = p ^ (row&7) pre-applied on src
#pragma unroll
    for (int i = 0; i < 4; i++) {
      int rl = i * 4 + b_rl_base;
      int c = b_p ^ (rl & 7);
      const float* fsrc = brow0 + (size_t)rl * S_ + kt + c * 4;
      gl2lds16((const u16*)fsrc, bbuf + i * 512);
    }
  };

  stage(&KV[0][0], &BiasL[0][w][0], 0);    // prologue: tile 0
  __syncthreads();

  int cur = 0;
#pragma unroll 1
  for (int t = 0; t < 16; t++) {
    int kt = t * 64;
    if (t < 15) stage(&KV[cur ^ 1][0], &BiasL[cur ^ 1][w][0], kt + 64);
    const u16* kvb = &KV[cur][0];
    const u16* bb = &BiasL[cur][w][0];

    // S^T = K Q^T: lane l16 owns q-row l16, keys g*16+quad*4+r
    f32x4 sg[4];
    __builtin_amdgcn_s_setprio(1);
#pragma unroll
    for (int g = 0; g < 4; g++) {
      int row = g * 16 + l16;
      int sw = quad ^ (row & 3);
      bf16x8 kf0 = *(const bf16x8*)(kvb + row * 32 + sw * 8);
      bf16x8 kf1 = *(const bf16x8*)(kvb + 2048 + row * 32 + sw * 8);
      f32x4 a = (f32x4)(0.0f);
      a = __builtin_amdgcn_mfma_f32_16x16x32_bf16(kf0, qf0, a, 0, 0, 0);
      a = __builtin_amdgcn_mfma_f32_16x16x32_bf16(kf1, qf1, a, 0, 0, 0);
      sg[g] = a;
    }
    __builtin_amdgcn_s_setprio(0);

    // bias (LDS, swizzled read) + fixed-ref exp; no shuffles, no branches
#pragma unroll
    for (int g = 0; g < 4; g++) {
      f32x4 bf4 = *(const f32x4*)(bb + (size_t)l16 * 128 + ((u32)((g * 4 + quad) ^ (l16 & 7))) * 8);
      float p0 = __expf(sg[g][0] + bf4[0] - FIXED_M);
      float p1 = __expf(sg[g][1] + bf4[1] - FIXED_M);
      float p2 = __expf(sg[g][2] + bf4[2] - FIXED_M);
      float p3 = __expf(sg[g][3] + bf4[3] - FIXED_M);
      lr += (p0 + p1) + (p2 + p3);
      ushort4 pw;
      pw.x = f2bf(p0); pw.y = f2bf(p1); pw.z = f2bf(p2); pw.w = f2bf(p3);
      *(ushort4*)(&Pl[w][l16 * 72 + g * 16 + quad * 4]) = pw;
    }

    // P relayout: wave-local LDS round trip (no barrier)
    bf16x8 pf0 = *(const bf16x8*)(&Pl[w][l16 * 72 + quad * 8]);
    bf16x8 pf1 = *(const bf16x8*)(&Pl[w][l16 * 72 + 32 + quad * 8]);

    // O += P V  (B-frag from V^T halves)
    __builtin_amdgcn_s_setprio(1);
#pragma unroll
    for (int nt = 0; nt < 4; nt++) {
      int row = nt * 16 + l16;
      int sw = quad ^ (row & 3);
      bf16x8 vf0 = *(const bf16x8*)(kvb + 4096 + row * 32 + sw * 8);
      bf16x8 vf1 = *(const bf16x8*)(kvb + 6144 + row * 32 + sw * 8);
      Oacc[nt] = __builtin_amdgcn_mfma_f32_16x16x32_bf16(pf0, vf0, Oacc[nt], 0, 0, 0);
      Oacc[nt] = __builtin_amdgcn_mfma_f32_16x16x32_bf16(pf1, vf1, Oacc[nt], 0, 0, 0);
    }
    __builtin_amdgcn_s_setprio(0);

    // drain tile t+1's DMA (full tile of flight) + publish across waves
    if (t < 15) {
      asm volatile("s_waitcnt vmcnt(0)" ::: "memory");
      __builtin_amdgcn_sched_barrier(0);
      __builtin_amdgcn_s_barrier();
    }
    cur ^= 1;
  }

  // row-sum: lane partials -> full sum over the 4 quads (keys partition)
  float s = lr;
  s += __shfl_xor(s, 16, 64);
  s += __shfl_xor(s, 32, 64);
  size_t obase = ((size_t)(b * S_) + q0 + w * 16) * D_ + h * HD_;
#pragma unroll
  for (int r = 0; r < 4; r++) {
    float inv = 1.0f / __shfl(s, quad * 4 + r, 64);
    int qr = quad * 4 + r;
#pragma unroll
    for (int nt = 0; nt < 4; nt++) {
      ctx[obase + (size_t)qr * D_ + nt * 16 + l16] = f2bf(Oacc[nt][r] * inv);
    }
  }
}

extern "C" void kernel_launch(void* const* d_in, const int* in_sizes, int n_in,
                              void* d_out, int out_size, void* d_ws, size_t ws_size,
                              hipStream_t stream) {
  const float* Wk   = (const float*)d_in[0];  // primals_1 [D,D] -> K proj
  const float* Wo   = (const float*)d_in[1];  // primals_2 [D,D] -> out proj
  const float* Wq   = (const float*)d_in[2];  // primals_3 [D,D] -> Q proj
  const float* Wv   = (const float*)d_in[3];  // primals_4 [D,D] -> V proj
  const float* g1   = (const float*)d_in[4];  // primals_5 [D]
  const float* Wf1  = (const float*)d_in[5];  // primals_6 [F,D]
  const float* Wf2  = (const float*)d_in[6];  // primals_7 [D,F]
  const float* g2   = (const float*)d_in[7];  // primals_8 [D]
  const float* X    = (const float*)d_in[8];  // primals_9 [B,S,D] fp32
  const float* bias = (const float*)d_in[9];  // primals_10 [B,H,S,S] fp32
  float* out = (float*)d_out;

  const size_t MD = (size_t)B_ * S_ * D_;       // 4,194,304
  u16* wbf   = (u16*)d_ws;
  u16* Wqkvb = wbf;               // [1536,512] = Wq|Wk|Wv
  u16* Wob   = wbf +  786432;
  u16* Wf1b  = wbf + 1048576;
  u16* Wf2b  = wbf + 2097152;
  u16* h     = wbf + 3145728;     // h, later h2
  u16* qkv   = h + MD;            // [8192][1536]; later x1
  u16* vtb   = qkv + 3 * MD;      // [B,H,64,S]
  u16* ctx   = vtb + MD;
  u16* ff    = ctx + MD;          // [8192][2048]
  u16* x1    = qkv;
  u16* h2    = h;

  dim3 blk(256);
  const int M = B_ * S_;

  // 0. weights -> bf16
  cvt_w_k<<<3072, blk, 0, stream>>>(Wq, Wk, Wv, Wo, Wf1, Wf2, wbf);

  // 1. h = rmsnorm(x, g1)
  rmsnorm_k<0><<<M, blk, 0, stream>>>(X, g1, h);

  // 2. qkv = h @ Wqkv^T  (M=8192, N=1536, K=512)
  dim3 gqkv(1536 / 128, M / 128);   // (12, 64) = 768 blocks, 3/CU
  gemm_mfma_k<0, 0, 0, 128><<<gqkv, blk, 0, stream>>>(h, Wqkvb, nullptr, qkv, M, 1536, D_);

  // 3. Vt = transpose(v)
  dim3 gt(S_ / 64, H_, B_);
  transpose_v_k<<<gt, blk, 0, stream>>>(qkv, vtb);

  // 4. ctx = softmax(q k^T + bias) v  (bias via global_load_lds DMA)
  dim3 ga(S_ / 64, H_, B_);           // (16,8,8) = 1024 blocks
  attn_v9_k<<<ga, blk, 0, stream>>>(qkv, vtb, bias, ctx);

  // 5. x1 = x + ctx @ Wo^T (fp32 residual, bf16 out)
  dim3 g512(D_ / 128, M / 128);
  gemm_mfma_k<0, 1, 0, 128><<<g512, blk, 0, stream>>>(ctx, Wob, X, x1, M, D_, D_);

  // 6. h2 = rmsnorm(x1, g2)
  rmsnorm_k<1><<<M, blk, 0, stream>>>(x1, g2, h2);

  // 7. ff = relu(h2 @ Wf1^T)
  dim3 gff1(F_ / 128, M / 128);     // (16, 64)
  gemm_mfma_k<1, 0, 0, 128><<<gff1, blk, 0, stream>>>(h2, Wf1b, nullptr, ff, M, F_, D_);

  // 8. out = x1 + ff @ Wf2^T (bf16 residual, fp32 out)
  gemm_mfma_k<0, 2, 1, 128><<<g512, blk, 0, stream>>>(ff, Wf2b, x1, out, M, D_, F_);
}

// Round 8
// 557.822 us; speedup vs baseline: 1.1100x; 1.0181x over previous
//
#include <hip/hip_runtime.h>

#define B_ 8
#define S_ 1024
#define D_ 512
#define H_ 8
#define HD_ 64
#define F_ 2048

typedef unsigned short u16;  // bf16 bit pattern
typedef unsigned int u32;
typedef __attribute__((ext_vector_type(8))) short bf16x8;
typedef __attribute__((ext_vector_type(4))) float f32x4;

__device__ __forceinline__ float bf2f(u16 u) {
  union { unsigned int i; float f; } v; v.i = ((unsigned int)u) << 16; return v.f;
}
__device__ __forceinline__ u16 f2bf(float f) {
  union { float f; unsigned int i; } v; v.f = f;
  unsigned int r = v.i + 0x7fffu + ((v.i >> 16) & 1u);  // round-nearest-even
  return (u16)(r >> 16);
}

__device__ __forceinline__ void gl2lds16(const u16* g, u16* lds) {
  __builtin_amdgcn_global_load_lds(
      (const __attribute__((address_space(1))) unsigned int*)g,
      (__attribute__((address_space(3))) unsigned int*)lds, 16, 0, 0);
}

// ---------------- weight fp32 -> bf16 conversion ----------------
__global__ __launch_bounds__(256) void cvt_w_k(const float* __restrict__ wq, const float* __restrict__ wk,
                                               const float* __restrict__ wv, const float* __restrict__ wo,
                                               const float* __restrict__ wf1, const float* __restrict__ wf2,
                                               u16* __restrict__ dst) {
  size_t gid = (size_t)blockIdx.x * 256 + threadIdx.x;
  size_t e0 = gid * 4;
  const float* src; size_t loc;
  if      (e0 <  262144) { src = wq;  loc = e0; }
  else if (e0 <  524288) { src = wk;  loc = e0 -  262144; }
  else if (e0 <  786432) { src = wv;  loc = e0 -  524288; }
  else if (e0 < 1048576) { src = wo;  loc = e0 -  786432; }
  else if (e0 < 2097152) { src = wf1; loc = e0 - 1048576; }
  else                   { src = wf2; loc = e0 - 2097152; }
  float4 v = *(const float4*)(src + loc);
  ushort4 o; o.x = f2bf(v.x); o.y = f2bf(v.y); o.z = f2bf(v.z); o.w = f2bf(v.w);
  *(ushort4*)(dst + e0) = o;
}

// ---------------- RMSNorm: one block per row of 512, vectorized ----------------
template <int IN_BF16>
__global__ __launch_bounds__(256) void rmsnorm_k(const void* __restrict__ xv,
                                                 const float* __restrict__ w,
                                                 u16* __restrict__ out) {
  int row = blockIdx.x;
  int tid = threadIdx.x;
  float x0, x1;
  if (IN_BF16) {
    u32 v = ((const u32*)((const u16*)xv + (size_t)row * D_))[tid];
    x0 = bf2f((u16)(v & 0xffffu)); x1 = bf2f((u16)(v >> 16));
  } else {
    float2 v = ((const float2*)((const float*)xv + (size_t)row * D_))[tid];
    x0 = v.x; x1 = v.y;
  }
  float s = x0 * x0 + x1 * x1;
#pragma unroll
  for (int off = 32; off >= 1; off >>= 1) s += __shfl_xor(s, off, 64);
  __shared__ float red[4];
  int lane = tid & 63, wid = tid >> 6;
  if (lane == 0) red[wid] = s;
  __syncthreads();
  float tot = red[0] + red[1] + red[2] + red[3];
  float inv = rsqrtf(tot * (1.0f / D_) + 1e-6f);
  float2 wv = ((const float2*)w)[tid];
  u32 o = (u32)f2bf(x0 * inv * wv.x) | ((u32)f2bf(x1 * inv * wv.y) << 16);
  ((u32*)(out + (size_t)row * D_))[tid] = o;
}

// ------------- MFMA GEMM (m97 structure), B-transposed form -------------
template <int RELU, int RMODE, int OF32, int BM>
__global__ __launch_bounds__(256) void gemm_mfma_k(const u16* __restrict__ A,
                                                   const u16* __restrict__ W,
                                                   const void* __restrict__ Rv,
                                                   void* __restrict__ Cv,
                                                   int M, int N, int K) {
  constexpr int MI  = BM / 32;       // acc fragments in M per wave
  constexpr int ACH = BM / 16;       // A chunks (16 rows each)
  __shared__ __align__(16) u16 As[BM * 32];
  __shared__ __align__(16) u16 Bs[128 * 32];
  int tid = threadIdx.x;
  int w = tid >> 6, l = tid & 63;
  int quad = l >> 4, l16 = l & 15;
  int m0 = blockIdx.y * BM, n0 = blockIdx.x * 128;
  int wr = (w >> 1) * (BM / 2), wc = (w & 1) * 64;

  int c_sw = (l & 3) ^ ((l >> 2) & 3);
  int r_in = l >> 2;
  int swz = quad ^ (l16 & 3);

  f32x4 acc[MI][4];
#pragma unroll
  for (int i = 0; i < MI; i++)
#pragma unroll
    for (int j = 0; j < 4; j++) acc[i][j] = (f32x4)(0.0f);

  for (int k0 = 0; k0 < K; k0 += 32) {
    __syncthreads();
#pragma unroll
    for (int t = 0; t < (ACH + 8) / 4; t++) {
      int ch = w * ((ACH + 8) / 4) + t;
      const u16* src; u16* dst;
      if (ch < ACH) { src = A + (size_t)(m0 + ch * 16 + r_in) * K;         dst = As + ch * 512; }
      else          { src = W + (size_t)(n0 + (ch - ACH) * 16 + r_in) * K; dst = Bs + (ch - ACH) * 512; }
      gl2lds16(src + k0 + c_sw * 8, dst);
    }
    __syncthreads();
    bf16x8 af[MI], bf[4];
#pragma unroll
    for (int i = 0; i < MI; i++)
      af[i] = *(const bf16x8*)(As + (wr + i * 16 + l16) * 32 + swz * 8);
#pragma unroll
    for (int j = 0; j < 4; j++)
      bf[j] = *(const bf16x8*)(Bs + (wc + j * 16 + l16) * 32 + swz * 8);
#pragma unroll
    for (int i = 0; i < MI; i++)
#pragma unroll
      for (int j = 0; j < 4; j++)
        acc[i][j] = __builtin_amdgcn_mfma_f32_16x16x32_bf16(af[i], bf[j], acc[i][j], 0, 0, 0);
  }

#pragma unroll
  for (int i = 0; i < MI; i++)
#pragma unroll
    for (int r = 0; r < 4; r++) {
      int mrow = m0 + wr + i * 16 + quad * 4 + r;
      size_t base = (size_t)mrow * N + n0 + wc + l16;
#pragma unroll
      for (int j = 0; j < 4; j++) {
        float v = acc[i][j][r];
        if (RELU) v = fmaxf(v, 0.0f);
        if (RMODE == 1) v += ((const float*)Rv)[base + j * 16];
        if (RMODE == 2) v += bf2f(((const u16*)Rv)[base + j * 16]);
        if (OF32) ((float*)Cv)[base + j * 16] = v;
        else      ((u16*)Cv)[base + j * 16]   = f2bf(v);
      }
    }
}

// ------------- V transpose: qkv v-cols -> Vt[b][h][d][s] -------------
__global__ __launch_bounds__(256) void transpose_v_k(const u16* __restrict__ qkv,
                                                     u16* __restrict__ vt) {
  __shared__ u16 T[64][72];  // [dim][key]
  int t = threadIdx.x;
  int s0 = blockIdx.x * 64, h = blockIdx.y, b = blockIdx.z;
  int skey = t >> 3, dch = (t & 7) * 8;
  int rot = dch >> 3;  // rotate write order so dch groups hit different banks
#pragma unroll
  for (int rnd = 0; rnd < 2; rnd++) {
    int s = s0 + skey + rnd * 32;
    bf16x8 vv = *(const bf16x8*)(qkv + ((size_t)(b * S_) + s) * 1536 + 1024 + h * HD_ + dch);
#pragma unroll
    for (int i = 0; i < 8; i++) {
      int ii = (i + rot) & 7;
      T[dch + ii][skey + rnd * 32] = (u16)((short*)&vv)[ii];
    }
  }
  __syncthreads();
  int d = t >> 2, kc = (t & 3) * 16;
  bf16x8 a0 = *(const bf16x8*)(&T[d][kc]);
  bf16x8 a1 = *(const bf16x8*)(&T[d][kc + 8]);
  u16* dst = vt + ((size_t)(b * H_ + h) * HD_ + d) * S_ + s0 + kc;
  *(bf16x8*)dst       = a0;
  *(bf16x8*)(dst + 8) = a1;
}

// ------------- attention v10: KVBLK=128, whole-row bias DMA bursts -------------
// Diagnosis (R7): attn tile-wall ~9800cy >> compute(600)+latency(900) ->
// DRAM-efficiency-bound. 64-key tiles made every bias DMA a 256B burst
// (4 rows/instr) with ~8K concurrent 4KB-strided streams -> row thrash,
// ~2.4 TB/s. Fix: 128-key tiles -> each bias DMA instr = 2 whole 512B rows
// (2x burst, 1/2 streams). Everything dbuf'd: Ks 2x16K + Vs 2x16K + Bias
// 2x32K + Pl 9.2K = 137 KB LDS (AITER attn uses 160 KB on gfx950), 1
// block/CU, 4 waves. G21 discipline everywhere: linear DMA dest +
// inverse-swizzled global src + XOR-swizzled reads (chunk^(row&7), 2-way).
#define FIXED_M 20.0f

__global__ __launch_bounds__(256, 1) void attn_v10_k(const u16* __restrict__ qkv,
                                                     const u16* __restrict__ vt,
                                                     const float* __restrict__ bias,
                                                     u16* __restrict__ ctx) {
  int tid = threadIdx.x;
  int w = tid >> 6, lane = tid & 63;
  int quad = lane >> 4, l16 = lane & 15;
  int h = blockIdx.y, b = blockIdx.z;
  int q0 = blockIdx.x * 64;   // 4 waves x 16 q-rows

  __shared__ __align__(16) u16 Ks[2][128 * 64];   // [dbuf][key][8 chunks x 16B dims]
  __shared__ __align__(16) u16 Vs[2][64 * 128];   // [dbuf][d][16 chunks x 16B keys]
  __shared__ __align__(16) u16 Bs[2][64 * 256];   // [dbuf][q][32 chunks x 16B fp32 keys]
  __shared__ __align__(16) u16 Pl[4][16 * 72];    // per-wave P [q][key], pad 64->72

  // Q frags (swapped layout: Q is the MFMA B operand)
  const u16* qrow = qkv + ((size_t)(b * S_) + q0 + w * 16 + l16) * 1536 + h * HD_;
  bf16x8 qf0 = *(const bf16x8*)(qrow + quad * 8);
  bf16x8 qf1 = *(const bf16x8*)(qrow + 32 + quad * 8);

  float lr = 0.0f;          // per-lane partial row-sum for q-row l16
  f32x4 Oacc[4];
#pragma unroll
  for (int nt = 0; nt < 4; nt++) Oacc[nt] = (f32x4)(0.0f);

  // ---- staging: K/V split across waves; bias rows are wave-private ----
  auto stage = [&](int buf, int kt) {
    // K: 128 keys x 128B rows; 16 instr of 8 rows; logical chunk c at phys p=c^(r&7)
#pragma unroll
    for (int i = 0; i < 4; i++) {
      int j = w * 4 + i;
      int kr = j * 8 + (lane >> 3);                 // tile-local key row
      int cs = (lane & 7) ^ (lane >> 3);            // src chunk for phys lane&7
      const u16* src = qkv + ((size_t)(b * S_) + kt + kr) * 1536 + 512 + h * HD_ + cs * 8;
      gl2lds16(src, &Ks[buf][j * 512]);
    }
    // V: 64 d x 256B rows; 16 instr of 4 rows
#pragma unroll
    for (int i = 0; i < 4; i++) {
      int j = w * 4 + i;
      int vr = j * 4 + (lane >> 4);
      int cs = (lane & 15) ^ (vr & 7);
      const u16* src = vt + ((size_t)((b * H_ + h) * HD_) + vr) * S_ + kt + cs * 8;
      gl2lds16(src, &Vs[buf][j * 512]);
    }
    // bias: per-wave 16 q-rows x 512B; 8 instr of 2 WHOLE rows (512B bursts)
#pragma unroll
    for (int i = 0; i < 8; i++) {
      int rq = i * 2 + (lane >> 5);                 // wave-local q row
      int cs = (lane & 31) ^ (rq & 7);
      const float* fsrc = bias + ((size_t)((b * H_ + h) * S_) + q0 + w * 16 + rq) * S_ + kt + cs * 4;
      gl2lds16((const u16*)fsrc, &Bs[buf][(w * 16 + i * 2) * 256]);
    }
  };

  stage(0, 0);
  __syncthreads();

  int cur = 0;
#pragma unroll 1
  for (int t = 0; t < 8; t++) {
    int kt = t * 128;
    if (t < 7) stage(cur ^ 1, kt + 128);
    const u16* Ksb = &Ks[cur][0];
    const u16* Vsb = &Vs[cur][0];
    const float* Bsb = (const float*)&Bs[cur][0];

#pragma unroll
    for (int s = 0; s < 2; s++) {
      // S^T = K Q^T: lane l16 owns q-row l16; keys (s*64+g*16)+quad*4+r
      f32x4 sg[4];
      __builtin_amdgcn_s_setprio(1);
#pragma unroll
      for (int g = 0; g < 4; g++) {
        int r = s * 64 + g * 16 + l16;              // r&7 == l16&7
        bf16x8 kf0 = *(const bf16x8*)(Ksb + r * 64 + ((quad ^ (l16 & 7)) * 8));
        bf16x8 kf1 = *(const bf16x8*)(Ksb + r * 64 + (((4 + quad) ^ (l16 & 7)) * 8));
        f32x4 a = (f32x4)(0.0f);
        a = __builtin_amdgcn_mfma_f32_16x16x32_bf16(kf0, qf0, a, 0, 0, 0);
        a = __builtin_amdgcn_mfma_f32_16x16x32_bf16(kf1, qf1, a, 0, 0, 0);
        sg[g] = a;
      }
      __builtin_amdgcn_s_setprio(0);

      // bias (LDS swizzled f32x4) + fixed-ref exp; no shuffles, no branches
#pragma unroll
      for (int g = 0; g < 4; g++) {
        int G = s * 4 + g;
        f32x4 bf4 = *(const f32x4*)(Bsb + (size_t)(w * 16 + l16) * 128 + (((G * 4 + quad) ^ (l16 & 7)) * 4));
        float p0 = __expf(sg[g][0] + bf4[0] - FIXED_M);
        float p1 = __expf(sg[g][1] + bf4[1] - FIXED_M);
        float p2 = __expf(sg[g][2] + bf4[2] - FIXED_M);
        float p3 = __expf(sg[g][3] + bf4[3] - FIXED_M);
        lr += (p0 + p1) + (p2 + p3);
        ushort4 pw;
        pw.x = f2bf(p0); pw.y = f2bf(p1); pw.z = f2bf(p2); pw.w = f2bf(p3);
        *(ushort4*)(&Pl[w][l16 * 72 + g * 16 + quad * 4]) = pw;
      }

      // P relayout: wave-local LDS round trip (no barrier)
      bf16x8 pf0 = *(const bf16x8*)(&Pl[w][l16 * 72 + quad * 8]);
      bf16x8 pf1 = *(const bf16x8*)(&Pl[w][l16 * 72 + 32 + quad * 8]);

      // O += P V  (B-frag from V^T)
      __builtin_amdgcn_s_setprio(1);
#pragma unroll
      for (int nt = 0; nt < 4; nt++) {
        int rv = nt * 16 + l16;                     // rv&7 == l16&7
        bf16x8 vf0 = *(const bf16x8*)(Vsb + rv * 128 + (((s * 8 + quad) ^ (l16 & 7)) * 8));
        bf16x8 vf1 = *(const bf16x8*)(Vsb + rv * 128 + (((s * 8 + 4 + quad) ^ (l16 & 7)) * 8));
        Oacc[nt] = __builtin_amdgcn_mfma_f32_16x16x32_bf16(pf0, vf0, Oacc[nt], 0, 0, 0);
        Oacc[nt] = __builtin_amdgcn_mfma_f32_16x16x32_bf16(pf1, vf1, Oacc[nt], 0, 0, 0);
      }
      __builtin_amdgcn_s_setprio(0);
    }

    __syncthreads();   // drains next tile's DMA + frees cur for t+2's stage
    cur ^= 1;
  }

  // row-sum: lane partials -> full sum over the 4 quads (keys partition)
  float s = lr;
  s += __shfl_xor(s, 16, 64);
  s += __shfl_xor(s, 32, 64);
  size_t obase = ((size_t)(b * S_) + q0 + w * 16) * D_ + h * HD_;
#pragma unroll
  for (int r = 0; r < 4; r++) {
    float inv = 1.0f / __shfl(s, quad * 4 + r, 64);
    int qr = quad * 4 + r;
#pragma unroll
    for (int nt = 0; nt < 4; nt++) {
      ctx[obase + (size_t)qr * D_ + nt * 16 + l16] = f2bf(Oacc[nt][r] * inv);
    }
  }
}

extern "C" void kernel_launch(void* const* d_in, const int* in_sizes, int n_in,
                              void* d_out, int out_size, void* d_ws, size_t ws_size,
                              hipStream_t stream) {
  const float* Wk   = (const float*)d_in[0];  // primals_1 [D,D] -> K proj
  const float* Wo   = (const float*)d_in[1];  // primals_2 [D,D] -> out proj
  const float* Wq   = (const float*)d_in[2];  // primals_3 [D,D] -> Q proj
  const float* Wv   = (const float*)d_in[3];  // primals_4 [D,D] -> V proj
  const float* g1   = (const float*)d_in[4];  // primals_5 [D]
  const float* Wf1  = (const float*)d_in[5];  // primals_6 [F,D]
  const float* Wf2  = (const float*)d_in[6];  // primals_7 [D,F]
  const float* g2   = (const float*)d_in[7];  // primals_8 [D]
  const float* X    = (const float*)d_in[8];  // primals_9 [B,S,D] fp32
  const float* bias = (const float*)d_in[9];  // primals_10 [B,H,S,S] fp32
  float* out = (float*)d_out;

  const size_t MD = (size_t)B_ * S_ * D_;       // 4,194,304
  u16* wbf   = (u16*)d_ws;
  u16* Wqkvb = wbf;               // [1536,512] = Wq|Wk|Wv
  u16* Wob   = wbf +  786432;
  u16* Wf1b  = wbf + 1048576;
  u16* Wf2b  = wbf + 2097152;
  u16* h     = wbf + 3145728;     // h, later h2
  u16* qkv   = h + MD;            // [8192][1536]; later x1
  u16* vtb   = qkv + 3 * MD;      // [B,H,64,S]
  u16* ctx   = vtb + MD;
  u16* ff    = ctx + MD;          // [8192][2048]
  u16* x1    = qkv;
  u16* h2    = h;

  dim3 blk(256);
  const int M = B_ * S_;

  // 0. weights -> bf16
  cvt_w_k<<<3072, blk, 0, stream>>>(Wq, Wk, Wv, Wo, Wf1, Wf2, wbf);

  // 1. h = rmsnorm(x, g1)
  rmsnorm_k<0><<<M, blk, 0, stream>>>(X, g1, h);

  // 2. qkv = h @ Wqkv^T  (M=8192, N=1536, K=512)
  dim3 gqkv(1536 / 128, M / 128);   // (12, 64) = 768 blocks, 3/CU
  gemm_mfma_k<0, 0, 0, 128><<<gqkv, blk, 0, stream>>>(h, Wqkvb, nullptr, qkv, M, 1536, D_);

  // 3. Vt = transpose(v)
  dim3 gt(S_ / 64, H_, B_);
  transpose_v_k<<<gt, blk, 0, stream>>>(qkv, vtb);

  // 4. ctx = softmax(q k^T + bias) v  (KVBLK=128, whole-row bias bursts)
  dim3 ga(S_ / 64, H_, B_);           // (16,8,8) = 1024 blocks, 1/CU
  attn_v10_k<<<ga, blk, 0, stream>>>(qkv, vtb, bias, ctx);

  // 5. x1 = x + ctx @ Wo^T (BM=64 -> 512 blocks, 2/CU; R1/R6: -12us vs BM=128)
  dim3 g512b(D_ / 128, M / 64);
  gemm_mfma_k<0, 1, 0, 64><<<g512b, blk, 0, stream>>>(ctx, Wob, X, x1, M, D_, D_);

  // 6. h2 = rmsnorm(x1, g2)
  rmsnorm_k<1><<<M, blk, 0, stream>>>(x1, g2, h2);

  // 7. ff = relu(h2 @ Wf1^T)
  dim3 gff1(F_ / 128, M / 128);     // (16, 64)
  gemm_mfma_k<1, 0, 0, 128><<<gff1, blk, 0, stream>>>(h2, Wf1b, nullptr, ff, M, F_, D_);

  // 8. out = x1 + ff @ Wf2^T (BM=64)
  gemm_mfma_k<0, 2, 1, 64><<<g512b, blk, 0, stream>>>(ff, Wf2b, x1, out, M, D_, F_);
}